// Round 3
// baseline (242.500 us; speedup 1.0000x reference)
//
#include <hip/hip_runtime.h>
#include <math.h>
#include <stdint.h>

#define NCLS   80
#define NPTS   8400
#define KEEP   100
#define PRETOPK 5000
#define NB     8
#define CAPS   2048     // candidate cap, sort_nms
#define CAPT   1024     // candidate cap, topk
#define TB     256      // sort_nms block size
#define NREG   33       // ceil(NPTS / TB)
#define THRBITS 0x3C23D70Au   // bits of 0.01f; keys are positive floats -> int-ordered

__device__ __forceinline__ float sigmoidf_(float x) { return 1.0f / (1.0f + expf(-x)); }

__device__ __forceinline__ void level_of(int n, int& base, int& W, int& HW, float& s, int& lvl) {
    if (n < 6400)      { lvl = 0; base = n;        W = 80; HW = 6400; s = 8.f;  }
    else if (n < 8000) { lvl = 1; base = n - 6400; W = 40; HW = 1600; s = 16.f; }
    else               { lvl = 2; base = n - 8000; W = 20; HW = 400;  s = 32.f; }
}

// ---------------------------------------------------------------- decode boxes
__global__ void decode_boxes(const float* __restrict__ bb0,
                             const float* __restrict__ bb1,
                             const float* __restrict__ bb2,
                             float4* __restrict__ boxes) {
    int t = blockIdx.x * blockDim.x + threadIdx.x;
    if (t >= NB * NPTS) return;
    int b = t / NPTS, n = t - b * NPTS;
    int base, W, HW, lvl; float s;
    level_of(n, base, W, HW, s, lvl);
    const float* bb = (lvl == 0) ? bb0 : ((lvl == 1) ? bb1 : bb2);
    const float* p = bb + (size_t)b * 4 * HW + base;
    float v0 = p[0], v1 = p[HW], v2 = p[2 * HW], v3 = p[3 * HW];
    int y = base / W, x = base - y * W;
    float px = x * s, py = y * s;
    float cx = v0 * s + px, cy = v1 * s + py;
    float w = expf(v2) * s, h = expf(v3) * s;
    boxes[t] = make_float4(cx - w * 0.5f, cy - h * 0.5f, cx + w * 0.5f, cy + h * 0.5f);
}

__device__ __forceinline__ bool iou_gt(float4 a, float4 c) {
    float tlx = fmaxf(a.x, c.x), tly = fmaxf(a.y, c.y);
    float brx = fminf(a.z, c.z), bry = fminf(a.w, c.w);
    float w = fmaxf(brx - tlx, 0.f), h = fmaxf(bry - tly, 0.f);
    float inter = w * h;
    float a1 = (a.z - a.x) * (a.w - a.y);
    float a2 = (c.z - c.x) * (c.w - c.y);
    return inter / (a1 + a2 - inter + 1e-6f) > 0.65f;
}

// ---------------------------------------------------------------- small bitonic (key desc, idx asc)
__device__ void bitonic_kv(uint32_t* key, uint16_t* idx, int P, int tid, int nthr) {
    for (int k = 2; k <= P; k <<= 1) {
        for (int j = k >> 1; j > 0; j >>= 1) {
            __syncthreads();
            for (int i = tid; i < (P >> 1); i += nthr) {
                int pos = ((i & ~(j - 1)) << 1) | (i & (j - 1));
                int par = pos | j;
                uint32_t ka = key[pos], kb = key[par];
                uint16_t ia = idx[pos], ib = idx[par];
                bool aBefore = (ka > kb) || (ka == kb && ia < ib);
                bool desc = ((pos & k) == 0);
                if (desc ? !aBefore : aBefore) {
                    key[pos] = kb; key[par] = ka;
                    idx[pos] = ib; idx[par] = ia;
                }
            }
        }
    }
    __syncthreads();
}

// ---------------------------------------------------------------- wave-0 scan over hist, find bin where desc-cumsum crosses `need`
// writes shr[0..3]; all 64 lanes of wave 0 call.
__device__ void scan_cross(const uint32_t* hist, int nb, uint32_t need, uint32_t cap,
                           uint32_t carry, uint32_t prefix, int shift, int level,
                           uint32_t* shr, int lane) {
    int foundBin = -1; uint32_t cAbove = 0, bCnt = 0;
    uint32_t run = carry;
    for (int hi = nb - 1; hi >= 0; hi -= 64) {
        int bin = hi - lane;
        uint32_t c = (bin >= 0) ? hist[bin] : 0u;
        uint32_t inc = c;
        #pragma unroll
        for (int d = 1; d < 64; d <<= 1) { uint32_t t = __shfl_up(inc, d); if (lane >= d) inc += t; }
        unsigned long long msk = __ballot((run + inc >= need) ? 1 : 0);
        if (msk) {
            int fl = (int)__ffsll(msk) - 1;
            uint32_t incF = __shfl(inc, fl);
            uint32_t cF   = __shfl(c, fl);
            foundBin = hi - fl;
            cAbove = run + incF - cF;
            bCnt = cF;
            break;
        }
        run += (uint32_t)__shfl(inc, 63);
    }
    if (lane == 0) {
        if (foundBin < 0) { shr[1] = 0u; shr[0] = 0u; }   // take-all (total < need <= cap)
        else {
            uint32_t cntIncl = cAbove + bCnt;
            if (level == 2 || cntIncl <= cap) {
                shr[1] = 0u; shr[0] = prefix | ((uint32_t)foundBin << shift);
            } else {
                shr[1] = 1u; shr[2] = prefix | ((uint32_t)foundBin << shift); shr[3] = cAbove;
            }
        }
    }
}

// ---------------------------------------------------------------- per-(b,c) select + NMS (keys in registers)
__global__ __launch_bounds__(TB)
void sort_nms(const float* __restrict__ cls0, const float* __restrict__ obj0,
              const float* __restrict__ cls1, const float* __restrict__ obj1,
              const float* __restrict__ cls2, const float* __restrict__ obj2,
              const float4* __restrict__ boxes,
              float* __restrict__ keptScore, float4* __restrict__ keptBox) {
    __shared__ uint32_t sHist[4096];                // 16384 B
    __shared__ uint32_t cKey[CAPS];                 // 8192 B
    __shared__ uint16_t cIdx[CAPS];                 // 4096 B
    __shared__ uint32_t shr[4];
    __shared__ int      sDone;

    int bc = blockIdx.x;
    int b = bc / NCLS, c = bc - b * NCLS;
    int tid = threadIdx.x;
    int lane = tid;                                  // meaningful for tid < 64

    // ---- build keys into registers: thread holds n = tid + i*TB
    uint32_t rKey[NREG];
    #pragma unroll
    for (int i = 0; i < NREG; ++i) {
        int n = tid + i * TB;
        uint32_t key = 0u;
        if (n < NPTS) {
            int base, W, HW, lvl; float s;
            level_of(n, base, W, HW, s, lvl);
            const float* clsP = (lvl == 0) ? cls0 : ((lvl == 1) ? cls1 : cls2);
            const float* objP = (lvl == 0) ? obj0 : ((lvl == 1) ? obj1 : obj2);
            float cv = clsP[((size_t)b * NCLS + c) * HW + base];
            float ov = objP[(size_t)b * HW + base];
            key = __float_as_uint(sigmoidf_(cv) * sigmoidf_(ov));  // (0,1): bit-order == float-order
        }
        rKey[i] = key;
    }

    uint32_t upper = 0xFFFFFFFFu;
    float4 kb0 = make_float4(0.f, 0.f, 0.f, 0.f), kb1 = kb0;
    float ks0 = -1.0f, ks1 = -1.0f;
    int K = 0, pos = 0;

    for (;;) {
        // ---------------- exact radix select (from registers)
        uint32_t prefix = 0, carry = 0, Tsel = 0;
        int level = 0;
        for (;;) {
            int shift = (level == 0) ? 18 : (level == 1 ? 6 : 0);
            int nb = (level == 2) ? 64 : 4096;
            __syncthreads();
            for (int i = tid; i < nb; i += TB) sHist[i] = 0;
            __syncthreads();
            #pragma unroll
            for (int i = 0; i < NREG; ++i) {
                uint32_t k = rKey[i];
                if (k > THRBITS && k < upper) {
                    if (level == 0) atomicAdd(&sHist[k >> 18], 1u);
                    else if (level == 1) { if ((k >> 18) == (prefix >> 18)) atomicAdd(&sHist[(k >> 6) & 0xFFFu], 1u); }
                    else { if ((k >> 6) == (prefix >> 6)) atomicAdd(&sHist[k & 0x3Fu], 1u); }
                }
            }
            __syncthreads();
            if (tid < 64) scan_cross(sHist, nb, 256u, CAPS, carry, prefix, shift, level, shr, lane);
            __syncthreads();
            if (shr[1] == 0u) { Tsel = shr[0]; break; }
            prefix = shr[2];
            carry = shr[3];
            level++;
        }
        __syncthreads();
        if (tid == 0) shr[3] = 0u;
        __syncthreads();
        #pragma unroll
        for (int i = 0; i < NREG; ++i) {
            uint32_t k = rKey[i];
            if (k > THRBITS && k < upper && k >= Tsel) {
                uint32_t s = atomicAdd(&shr[3], 1u);
                if (s < CAPS) { cKey[s] = k; cIdx[s] = (uint16_t)(tid + i * TB); }
            }
        }
        __syncthreads();
        int cnt = (int)shr[3]; if (cnt > CAPS) cnt = CAPS;
        if (cnt == 0) break;

        // ---------------- sort candidates (desc, idx asc)
        int P = 64; while (P < cnt) P <<= 1;
        for (int i = cnt + tid; i < P; i += TB) { cKey[i] = 0u; cIdx[i] = 0xFFFF; }
        bitonic_kv(cKey, cIdx, P, tid, TB);          // starts & ends with __syncthreads

        // ---------------- wave-0 prefetch first 256 candidates into registers
        float4 rb[4]; uint32_t rk[4];
        if (tid < 64) {
            #pragma unroll
            for (int q = 0; q < 4; ++q) {
                int p = q * 64 + lane;
                if (p < cnt) { rk[q] = cKey[p]; rb[q] = boxes[(size_t)b * NPTS + cIdx[p]]; }
                else         { rk[q] = 0u; rb[q] = make_float4(0.f, 0.f, 0.f, 0.f); }
            }
        }
        if (tid == 0) sDone = 0;
        __syncthreads();

        // ---------------- serial greedy walk on wave 0 (shfl-broadcast candidates)
        if (tid < 64) {
            bool stop = false;
            #pragma unroll
            for (int q = 0; q < 4; ++q) {
                if (stop) break;
                int pbase = q * 64;
                if (pbase >= cnt) break;
                float4 cb = rb[q]; uint32_t ck = rk[q];
                int lim = cnt - pbase; if (lim > 64) lim = 64;
                for (int s = 0; s < lim; ++s) {
                    if (pos >= PRETOPK) { stop = true; break; }
                    float4 box;
                    box.x = __shfl(cb.x, s); box.y = __shfl(cb.y, s);
                    box.z = __shfl(cb.z, s); box.w = __shfl(cb.w, s);
                    uint32_t kk = __shfl(ck, s);
                    pos++;
                    bool sup = false;
                    if (lane < K)      sup = iou_gt(box, kb0);
                    if (64 + lane < K) sup = sup || iou_gt(box, kb1);
                    if (!__any(sup ? 1 : 0)) {
                        float sc = __uint_as_float(kk);
                        if (K < 64) { if (lane == K)      { kb0 = box; ks0 = sc; } }
                        else        { if (lane == K - 64) { kb1 = box; ks1 = sc; } }
                        K++;
                        if (K >= KEEP) { stop = true; break; }
                    }
                }
            }
            // tail beyond the 256 register-resident candidates (rare)
            for (int p = 256; p < cnt && !stop; ++p) {
                if (pos >= PRETOPK) { stop = true; break; }
                uint32_t kk = cKey[p];
                float4 box = boxes[(size_t)b * NPTS + cIdx[p]];
                pos++;
                bool sup = false;
                if (lane < K)      sup = iou_gt(box, kb0);
                if (64 + lane < K) sup = sup || iou_gt(box, kb1);
                if (!__any(sup ? 1 : 0)) {
                    float sc = __uint_as_float(kk);
                    if (K < 64) { if (lane == K)      { kb0 = box; ks0 = sc; } }
                    else        { if (lane == K - 64) { kb1 = box; ks1 = sc; } }
                    K++;
                    if (K >= KEEP) stop = true;
                }
            }
            if (lane == 0 && stop) sDone = 1;
        }
        __syncthreads();
        if (sDone) break;
        upper = Tsel;
    }

    if (tid < 64) {
        int off = (b * NCLS + c) * KEEP;
        float4 z = make_float4(0.f, 0.f, 0.f, 0.f);
        keptScore[off + lane] = (lane < K) ? ks0 : -1.0f;
        keptBox[off + lane]   = (lane < K) ? kb0 : z;
        if (64 + lane < KEEP) {
            keptScore[off + 64 + lane] = (64 + lane < K) ? ks1 : -1.0f;
            keptBox[off + 64 + lane]   = (64 + lane < K) ? kb1 : z;
        }
    }
}

// ---------------------------------------------------------------- per-image global top-100
__global__ __launch_bounds__(1024)
void topk_out(const float* __restrict__ keptScore, const float4* __restrict__ keptBox,
              float* __restrict__ out) {
    __shared__ uint32_t sKey[NCLS * KEEP];          // 32000 B
    __shared__ uint32_t sHist[4096];                // 16384 B
    __shared__ uint32_t cKey[CAPT];                 // 4096 B
    __shared__ uint16_t cIdx[CAPT];                 // 2048 B
    __shared__ uint32_t shr[4];
    int b = blockIdx.x, tid = threadIdx.x;
    int lane = tid & 63;
    const int TOT = NCLS * KEEP;                    // 8000

    for (int i = tid; i < TOT; i += 1024) {
        float s = keptScore[b * TOT + i];
        sKey[i] = (s > 0.f) ? __float_as_uint(s) : 0u;   // invalid -> 0 (filtered by thr=0)
    }
    __syncthreads();

    // exact radix select, need=KEEP
    uint32_t prefix = 0, carry = 0, Tsel = 0;
    int level = 0;
    for (;;) {
        int shift = (level == 0) ? 18 : (level == 1 ? 6 : 0);
        int nb = (level == 2) ? 64 : 4096;
        __syncthreads();
        for (int i = tid; i < nb; i += 1024) sHist[i] = 0;
        __syncthreads();
        for (int n = tid; n < TOT; n += 1024) {
            uint32_t k = sKey[n];
            if (k > 0u && k < 0xFFFFFFFFu) {
                if (level == 0) atomicAdd(&sHist[k >> 18], 1u);
                else if (level == 1) { if ((k >> 18) == (prefix >> 18)) atomicAdd(&sHist[(k >> 6) & 0xFFFu], 1u); }
                else { if ((k >> 6) == (prefix >> 6)) atomicAdd(&sHist[k & 0x3Fu], 1u); }
            }
        }
        __syncthreads();
        if (tid < 64) scan_cross(sHist, nb, (uint32_t)KEEP, CAPT, carry, prefix, shift, level, shr, lane);
        __syncthreads();
        if (shr[1] == 0u) { Tsel = shr[0]; break; }
        prefix = shr[2];
        carry = shr[3];
        level++;
    }
    __syncthreads();
    if (tid == 0) shr[3] = 0u;
    __syncthreads();
    for (int n = tid; n < TOT; n += 1024) {
        uint32_t k = sKey[n];
        if (k > 0u && k >= Tsel) {
            uint32_t s = atomicAdd(&shr[3], 1u);
            if (s < CAPT) { cKey[s] = k; cIdx[s] = (uint16_t)n; }
        }
    }
    __syncthreads();
    int cnt = (int)shr[3]; if (cnt > CAPT) cnt = CAPT;

    int P = 128; while (P < cnt) P <<= 1;
    for (int i = cnt + tid; i < P; i += 1024) { cKey[i] = 0u; cIdx[i] = 0xFFFF; }
    bitonic_kv(cKey, cIdx, P, tid, 1024);

    if (tid < KEEP) {
        bool valid = tid < cnt;
        int fi = valid ? (int)cIdx[tid] : 0;
        float sc = valid ? __uint_as_float(cKey[tid]) : 0.f;
        float4 bx = valid ? keptBox[b * TOT + fi] : make_float4(0.f, 0.f, 0.f, 0.f);
        float cls = valid ? (float)(fi / KEEP) : -1.0f;
        float* boxOut = out + NB + (b * KEEP + tid) * 4;
        boxOut[0] = bx.x; boxOut[1] = bx.y; boxOut[2] = bx.z; boxOut[3] = bx.w;
        out[NB + NB * KEEP * 4 + b * KEEP + tid] = sc;
        out[NB + NB * KEEP * 4 + NB * KEEP + b * KEEP + tid] = cls;
    }
    if (tid == 0) out[b] = (float)((cnt < KEEP) ? cnt : KEEP);
}

// ---------------------------------------------------------------- launch
extern "C" void kernel_launch(void* const* d_in, const int* in_sizes, int n_in,
                              void* d_out, int out_size, void* d_ws, size_t ws_size,
                              hipStream_t stream) {
    const float* cls0 = (const float*)d_in[0];
    const float* bb0  = (const float*)d_in[1];
    const float* obj0 = (const float*)d_in[2];
    const float* cls1 = (const float*)d_in[3];
    const float* bb1  = (const float*)d_in[4];
    const float* obj1 = (const float*)d_in[5];
    const float* cls2 = (const float*)d_in[6];
    const float* bb2  = (const float*)d_in[7];
    const float* obj2 = (const float*)d_in[8];
    float* out = (float*)d_out;

    char* ws = (char*)d_ws;
    float4* boxes     = (float4*)ws;                    // 8*8400*16 = 1,075,200 B
    float*  keptScore = (float*)(ws + 1075200);         // 8*80*100*4 = 256,000 B
    float4* keptBox   = (float4*)(ws + 1331200);        // 8*80*100*16 = 1,024,000 B

    decode_boxes<<<(NB * NPTS + 255) / 256, 256, 0, stream>>>(bb0, bb1, bb2, boxes);
    sort_nms<<<NB * NCLS, TB, 0, stream>>>(cls0, obj0, cls1, obj1, cls2, obj2,
                                           boxes, keptScore, keptBox);
    topk_out<<<NB, 1024, 0, stream>>>(keptScore, keptBox, out);
}

// Round 4
// 219.243 us; speedup vs baseline: 1.1061x; 1.1061x over previous
//
#include <hip/hip_runtime.h>
#include <math.h>
#include <stdint.h>

#define NCLS   80
#define NPTS   8400
#define KEEP   100
#define PRETOPK 5000
#define NB     8
#define THRBITS 0x3C23D70Au   // bits of 0.01f (scores are positive floats -> int-ordered)

#define TBA    512            // select_cands block size
#define NREGA  17             // ceil(8400/512)
#define CAPA   2048           // compaction cap
#define NEEDA  256u           // selection target
#define SCAP   512            // candidates written per class

#define TBB    256            // nms_walk block size
#define NREGB  33             // ceil(8400/256) for last-resort recompute
#define MTX    192            // bitmask-matrix candidate count

__device__ __forceinline__ float sigmoidf_(float x) { return 1.0f / (1.0f + expf(-x)); }

__device__ __forceinline__ void level_of(int n, int& base, int& W, int& HW, float& s, int& lvl) {
    if (n < 6400)      { lvl = 0; base = n;        W = 80; HW = 6400; s = 8.f;  }
    else if (n < 8000) { lvl = 1; base = n - 6400; W = 40; HW = 1600; s = 16.f; }
    else               { lvl = 2; base = n - 8000; W = 20; HW = 400;  s = 32.f; }
}

__device__ __forceinline__ uint32_t score_key(int n, int b, int c,
        const float* cls0, const float* obj0, const float* cls1, const float* obj1,
        const float* cls2, const float* obj2) {
    int base, W, HW, lvl; float s;
    level_of(n, base, W, HW, s, lvl);
    const float* clsP = (lvl == 0) ? cls0 : ((lvl == 1) ? cls1 : cls2);
    const float* objP = (lvl == 0) ? obj0 : ((lvl == 1) ? obj1 : obj2);
    float cv = clsP[((size_t)b * NCLS + c) * HW + base];
    float ov = objP[(size_t)b * HW + base];
    return __float_as_uint(sigmoidf_(cv) * sigmoidf_(ov));
}

// ---------------------------------------------------------------- decode boxes
__global__ void decode_boxes(const float* __restrict__ bb0,
                             const float* __restrict__ bb1,
                             const float* __restrict__ bb2,
                             float4* __restrict__ boxes) {
    int t = blockIdx.x * blockDim.x + threadIdx.x;
    if (t >= NB * NPTS) return;
    int b = t / NPTS, n = t - b * NPTS;
    int base, W, HW, lvl; float s;
    level_of(n, base, W, HW, s, lvl);
    const float* bb = (lvl == 0) ? bb0 : ((lvl == 1) ? bb1 : bb2);
    const float* p = bb + (size_t)b * 4 * HW + base;
    float v0 = p[0], v1 = p[HW], v2 = p[2 * HW], v3 = p[3 * HW];
    int y = base / W, x = base - y * W;
    float px = x * s, py = y * s;
    float cx = v0 * s + px, cy = v1 * s + py;
    float w = expf(v2) * s, h = expf(v3) * s;
    boxes[t] = make_float4(cx - w * 0.5f, cy - h * 0.5f, cx + w * 0.5f, cy + h * 0.5f);
}

__device__ __forceinline__ bool iou_gt(float4 a, float4 c) {
    float tlx = fmaxf(a.x, c.x), tly = fmaxf(a.y, c.y);
    float brx = fminf(a.z, c.z), bry = fminf(a.w, c.w);
    float w = fmaxf(brx - tlx, 0.f), h = fmaxf(bry - tly, 0.f);
    float inter = w * h;
    float a1 = (a.z - a.x) * (a.w - a.y);
    float a2 = (c.z - c.x) * (c.w - c.y);
    return inter / (a1 + a2 - inter + 1e-6f) > 0.65f;
}

// ---------------------------------------------------------------- bitonic (key desc, idx asc)
__device__ void bitonic_kv(uint32_t* key, uint16_t* idx, int P, int tid, int nthr) {
    for (int k = 2; k <= P; k <<= 1) {
        for (int j = k >> 1; j > 0; j >>= 1) {
            __syncthreads();
            for (int i = tid; i < (P >> 1); i += nthr) {
                int pos = ((i & ~(j - 1)) << 1) | (i & (j - 1));
                int par = pos | j;
                uint32_t ka = key[pos], kb = key[par];
                uint16_t ia = idx[pos], ib = idx[par];
                bool aBefore = (ka > kb) || (ka == kb && ia < ib);
                bool desc = ((pos & k) == 0);
                if (desc ? !aBefore : aBefore) {
                    key[pos] = kb; key[par] = ka;
                    idx[pos] = ib; idx[par] = ia;
                }
            }
        }
    }
    __syncthreads();
}

// ---------------------------------------------------------------- wave-0 crossing scan
__device__ void scan_cross(const uint32_t* hist, int nb, uint32_t need, uint32_t cap,
                           uint32_t carry, uint32_t prefix, int shift, int level,
                           uint32_t* shr, int lane) {
    int foundBin = -1; uint32_t cAbove = 0, bCnt = 0;
    uint32_t run = carry;
    for (int hi = nb - 1; hi >= 0; hi -= 64) {
        int bin = hi - lane;
        uint32_t c = (bin >= 0) ? hist[bin] : 0u;
        uint32_t inc = c;
        #pragma unroll
        for (int d = 1; d < 64; d <<= 1) { uint32_t t = __shfl_up(inc, d); if (lane >= d) inc += t; }
        unsigned long long msk = __ballot((run + inc >= need) ? 1 : 0);
        if (msk) {
            int fl = (int)__ffsll(msk) - 1;
            uint32_t incF = __shfl(inc, fl);
            uint32_t cF   = __shfl(c, fl);
            foundBin = hi - fl;
            cAbove = run + incF - cF;
            bCnt = cF;
            break;
        }
        run += (uint32_t)__shfl(inc, 63);
    }
    if (lane == 0) {
        if (foundBin < 0) { shr[1] = 0u; shr[0] = 0u; }   // take-all: total < need
        else {
            uint32_t cntIncl = cAbove + bCnt;
            if (cntIncl <= cap) { shr[1] = 0u; shr[0] = prefix | ((uint32_t)foundBin << shift); }
            else if (level == 2) { shr[1] = 0u; shr[0] = (prefix | (uint32_t)foundBin) + 1u; } // exclude fat tie-bin
            else { shr[1] = 1u; shr[2] = prefix | ((uint32_t)foundBin << shift); shr[3] = cAbove; }
        }
    }
}

// ---------------------------------------------------------------- A: per-(b,c) select + sort top-512
__global__ __launch_bounds__(TBA)
void select_cands(const float* __restrict__ cls0, const float* __restrict__ obj0,
                  const float* __restrict__ cls1, const float* __restrict__ obj1,
                  const float* __restrict__ cls2, const float* __restrict__ obj2,
                  uint32_t* __restrict__ candKey, uint16_t* __restrict__ candIdx,
                  uint32_t* __restrict__ meta) {
    __shared__ uint32_t sHist[4096];
    __shared__ uint32_t cKey[CAPA];
    __shared__ uint16_t cIdx[CAPA];
    __shared__ uint32_t shr[4];

    int bc = blockIdx.x;
    int b = bc / NCLS, c = bc - b * NCLS;
    int tid = threadIdx.x, lane = tid & 63;

    uint32_t rKey[NREGA];
    #pragma unroll
    for (int i = 0; i < NREGA; ++i) {
        int n = tid + i * TBA;
        rKey[i] = (n < NPTS) ? score_key(n, b, c, cls0, obj0, cls1, obj1, cls2, obj2) : 0u;
    }

    uint32_t prefix = 0, carry = 0, Tsel = 0;
    for (int level = 0;; ++level) {
        int shift = (level == 0) ? 18 : (level == 1 ? 6 : 0);
        int nb = (level == 2) ? 64 : 4096;
        __syncthreads();
        for (int i = tid; i < nb; i += TBA) sHist[i] = 0;
        __syncthreads();
        #pragma unroll
        for (int i = 0; i < NREGA; ++i) {
            uint32_t k = rKey[i];
            if (k > THRBITS) {
                if (level == 0) atomicAdd(&sHist[k >> 18], 1u);
                else if (level == 1) { if ((k >> 18) == (prefix >> 18)) atomicAdd(&sHist[(k >> 6) & 0xFFFu], 1u); }
                else { if ((k >> 6) == (prefix >> 6)) atomicAdd(&sHist[k & 0x3Fu], 1u); }
            }
        }
        __syncthreads();
        if (tid < 64) scan_cross(sHist, nb, NEEDA, CAPA, carry, prefix, shift, level, shr, lane);
        __syncthreads();
        if (shr[1] == 0u) { Tsel = shr[0]; break; }
        prefix = shr[2]; carry = shr[3];
    }
    __syncthreads();
    if (tid == 0) shr[3] = 0u;
    __syncthreads();
    #pragma unroll
    for (int i = 0; i < NREGA; ++i) {
        uint32_t k = rKey[i];
        if (k > THRBITS && k >= Tsel) {
            uint32_t s = atomicAdd(&shr[3], 1u);
            if (s < CAPA) { cKey[s] = k; cIdx[s] = (uint16_t)(tid + i * TBA); }
        }
    }
    __syncthreads();
    int cnt = (int)shr[3]; if (cnt > CAPA) cnt = CAPA;

    int P = 64; while (P < cnt) P <<= 1;
    for (int i = cnt + tid; i < P; i += TBA) { cKey[i] = 0u; cIdx[i] = 0xFFFF; }
    bitonic_kv(cKey, cIdx, P, tid, TBA);

    int S = (cnt < SCAP) ? cnt : SCAP;
    for (int s = tid; s < S; s += TBA) {
        candKey[bc * SCAP + s] = cKey[s];
        candIdx[bc * SCAP + s] = cIdx[s];
    }
    if (tid == 0) meta[bc] = (uint32_t)S;
}

// ---------------------------------------------------------------- B: bitmask-matrix NMS walk
__global__ __launch_bounds__(TBB)
void nms_walk(const float* __restrict__ cls0, const float* __restrict__ obj0,
              const float* __restrict__ cls1, const float* __restrict__ obj1,
              const float* __restrict__ cls2, const float* __restrict__ obj2,
              const float4* __restrict__ boxes,
              const uint32_t* __restrict__ candKey, const uint16_t* __restrict__ candIdx,
              const uint32_t* __restrict__ meta,
              float* __restrict__ keptScore, float4* __restrict__ keptBox) {
    __shared__ uint32_t bKey[SCAP];
    __shared__ uint16_t bIdx[SCAP];
    __shared__ float4   bBox[SCAP];
    __shared__ unsigned long long rows[MTX][4];
    __shared__ uint32_t shr[4];
    __shared__ unsigned long long sh64;

    int bc = blockIdx.x;
    int b = bc / NCLS, c = bc - b * NCLS;
    int tid = threadIdx.x, lane = tid & 63;

    int S = (int)meta[bc];
    for (int s = tid; s < S; s += TBB) {
        uint32_t k = candKey[bc * SCAP + s];
        uint16_t id = candIdx[bc * SCAP + s];
        bKey[s] = k; bIdx[s] = id;
        bBox[s] = boxes[(size_t)b * NPTS + id];
    }
    __syncthreads();

    int lim1 = (S < MTX) ? S : MTX;
    if (tid < lim1) {                      // parallel upper-triangle IoU bitmask
        int i = tid;
        float4 bi = bBox[i];
        unsigned long long w0 = 0, w1 = 0, w2 = 0;
        for (int j = i + 1; j < lim1; ++j) {
            if (iou_gt(bBox[j], bi)) {
                unsigned long long bit = 1ull << (j & 63);
                if (j < 64) w0 |= bit; else if (j < 128) w1 |= bit; else w2 |= bit;
            }
        }
        rows[i][0] = w0; rows[i][1] = w1; rows[i][2] = w2; rows[i][3] = 0;
    }
    __syncthreads();

    float4 kb0 = make_float4(0.f, 0.f, 0.f, 0.f), kb1 = kb0;
    float ks0 = -1.0f, ks1 = -1.0f;
    int K = 0, e = 0;

    if (tid < 64) {
        unsigned long long S0 = 0, S1 = 0, S2 = 0;
        for (int i = 0; i < lim1; ++i) {
            unsigned long long w = (i < 64) ? (S0 >> i) : (i < 128) ? (S1 >> (i - 64)) : (S2 >> (i - 128));
            e++;
            if (!(w & 1ull)) {
                S0 |= rows[i][0]; S1 |= rows[i][1]; S2 |= rows[i][2];
                float sc = __uint_as_float(bKey[i]);
                float4 bx = bBox[i];
                if (K < 64) { if (lane == K)      { kb0 = bx; ks0 = sc; } }
                else        { if (lane == K - 64) { kb1 = bx; ks1 = sc; } }
                K++;
                if (K >= KEEP) break;
            }
        }
        for (int i = e; i < S && K < KEEP; ++i) {   // mid-walk beyond matrix (rare)
            float4 bx = bBox[i]; uint32_t kk = bKey[i];
            e++;
            bool sup = false;
            if (lane < K)      sup = iou_gt(bx, kb0);
            if (64 + lane < K) sup = sup || iou_gt(bx, kb1);
            if (!__any(sup ? 1 : 0)) {
                float sc = __uint_as_float(kk);
                if (K < 64) { if (lane == K)      { kb0 = bx; ks0 = sc; } }
                else        { if (lane == K - 64) { kb1 = bx; ks1 = sc; } }
                K++;
            }
        }
        if (lane == 0) {
            shr[0] = (uint32_t)K; shr[1] = (uint32_t)e;
            shr[2] = (e > 0) ? bKey[e - 1] : 0xFFFFFFFFu;
            shr[3] = (e > 0) ? (uint32_t)bIdx[e - 1] : 0xFFFFFFFFu;
        }
    }
    __syncthreads();
    int Kall = (int)shr[0], eAll = (int)shr[1];
    uint32_t cK = shr[2], cI = shr[3];

    if (Kall < KEEP && eAll < PRETOPK) {            // last-resort exact continuation (≈never)
        uint32_t rk[NREGB];
        #pragma unroll
        for (int i = 0; i < NREGB; ++i) {
            int n = tid + i * TBB;
            rk[i] = (n < NPTS) ? score_key(n, b, c, cls0, obj0, cls1, obj1, cls2, obj2) : 0u;
        }
        for (;;) {
            if (tid == 0) sh64 = 0ull;
            __syncthreads();
            unsigned long long best = 0ull;
            #pragma unroll
            for (int i = 0; i < NREGB; ++i) {
                uint32_t k = rk[i]; int n = tid + i * TBB;
                if (k > THRBITS && (k < cK || (k == cK && (uint32_t)n > cI))) {
                    unsigned long long v = ((unsigned long long)k << 32) | (unsigned long long)(NPTS - 1 - n);
                    if (v > best) best = v;
                }
            }
            if (best) atomicMax(&sh64, best);
            __syncthreads();
            unsigned long long bv = sh64;
            if (bv == 0ull) break;
            uint32_t k = (uint32_t)(bv >> 32);
            int n = NPTS - 1 - (int)(bv & 0xFFFFFFFFull);
            if (tid < 64) {
                float4 bx = boxes[(size_t)b * NPTS + n];
                bool sup = false;
                if (lane < K)      sup = iou_gt(bx, kb0);
                if (64 + lane < K) sup = sup || iou_gt(bx, kb1);
                if (!__any(sup ? 1 : 0)) {
                    float sc = __uint_as_float(k);
                    if (K < 64) { if (lane == K)      { kb0 = bx; ks0 = sc; } }
                    else        { if (lane == K - 64) { kb1 = bx; ks1 = sc; } }
                    K++;
                }
                e++;
                if (lane == 0) { shr[0] = (uint32_t)K; shr[1] = (uint32_t)e; }
            }
            __syncthreads();
            Kall = (int)shr[0]; eAll = (int)shr[1];
            cK = k; cI = (uint32_t)n;
            if (Kall >= KEEP || eAll >= PRETOPK) break;
        }
    }

    if (tid < 64) {
        int off = (b * NCLS + c) * KEEP;
        float4 z = make_float4(0.f, 0.f, 0.f, 0.f);
        keptScore[off + lane] = (lane < K) ? ks0 : -1.0f;
        keptBox[off + lane]   = (lane < K) ? kb0 : z;
        if (64 + lane < KEEP) {
            keptScore[off + 64 + lane] = (64 + lane < K) ? ks1 : -1.0f;
            keptBox[off + 64 + lane]   = (64 + lane < K) ? kb1 : z;
        }
    }
}

// ---------------------------------------------------------------- topk stage A: per (image, 10-class chunk) top-100
__global__ __launch_bounds__(256)
void topk_a(const float* __restrict__ keptScore,
            uint32_t* __restrict__ tkKey, uint32_t* __restrict__ tkIdx) {
    __shared__ uint32_t tKey[1024];
    __shared__ uint16_t tIdx[1024];
    int bc = blockIdx.x;
    int b = bc >> 3, ch = bc & 7;
    int tid = threadIdx.x;

    for (int i = tid; i < 1024; i += 256) {
        uint32_t key = 0u; uint16_t id = 0xFFFF;
        if (i < 1000) {
            float s = keptScore[b * (NCLS * KEEP) + ch * 1000 + i];
            key = (s > 0.f) ? __float_as_uint(s) : 0u;
            id = (uint16_t)i;
        }
        tKey[i] = key; tIdx[i] = id;
    }
    bitonic_kv(tKey, tIdx, 1024, tid, 256);

    if (tid < KEEP) {
        uint32_t key = tKey[tid];
        uint32_t fi = (key > 0u) ? (uint32_t)(ch * 1000 + (int)tIdx[tid]) : 0u;
        tkKey[bc * KEEP + tid] = key;
        tkIdx[bc * KEEP + tid] = fi;
    }
}

// ---------------------------------------------------------------- topk stage B: per image top-100 of 800 + output
__global__ __launch_bounds__(256)
void topk_b(const uint32_t* __restrict__ tkKey, const uint32_t* __restrict__ tkIdx,
            const float4* __restrict__ keptBox, float* __restrict__ out) {
    __shared__ uint32_t tKey[1024];
    __shared__ uint16_t tIdx[1024];
    __shared__ int cnt;
    int b = blockIdx.x, tid = threadIdx.x;
    const int TOT = NCLS * KEEP;

    for (int i = tid; i < 1024; i += 256) {
        uint32_t key = 0u; uint16_t id = 0xFFFF;
        if (i < 800) {
            key = tkKey[b * 800 + i];
            id = (uint16_t)tkIdx[b * 800 + i];
        }
        tKey[i] = key; tIdx[i] = id;
    }
    if (tid == 0) cnt = 0;
    bitonic_kv(tKey, tIdx, 1024, tid, 256);

    if (tid < KEEP) {
        uint32_t key = tKey[tid];
        bool valid = key > 0u;
        int fi = valid ? (int)tIdx[tid] : 0;
        float sc = valid ? __uint_as_float(key) : 0.f;
        float4 bx = valid ? keptBox[b * TOT + fi] : make_float4(0.f, 0.f, 0.f, 0.f);
        float cls = valid ? (float)(fi / KEEP) : -1.0f;
        float* boxOut = out + NB + (b * KEEP + tid) * 4;
        boxOut[0] = bx.x; boxOut[1] = bx.y; boxOut[2] = bx.z; boxOut[3] = bx.w;
        out[NB + NB * KEEP * 4 + b * KEEP + tid] = sc;
        out[NB + NB * KEEP * 4 + NB * KEEP + b * KEEP + tid] = cls;
        if (valid) atomicAdd(&cnt, 1);
    }
    __syncthreads();
    if (tid == 0) out[b] = (float)cnt;
}

// ---------------------------------------------------------------- launch
extern "C" void kernel_launch(void* const* d_in, const int* in_sizes, int n_in,
                              void* d_out, int out_size, void* d_ws, size_t ws_size,
                              hipStream_t stream) {
    const float* cls0 = (const float*)d_in[0];
    const float* bb0  = (const float*)d_in[1];
    const float* obj0 = (const float*)d_in[2];
    const float* cls1 = (const float*)d_in[3];
    const float* bb1  = (const float*)d_in[4];
    const float* obj1 = (const float*)d_in[5];
    const float* cls2 = (const float*)d_in[6];
    const float* bb2  = (const float*)d_in[7];
    const float* obj2 = (const float*)d_in[8];
    float* out = (float*)d_out;

    char* ws = (char*)d_ws;
    float4*   boxes     = (float4*)(ws);                 // 1,075,200
    float*    keptScore = (float*)(ws + 1075200);        //   256,000
    float4*   keptBox   = (float4*)(ws + 1331200);       // 1,024,000
    uint32_t* candKey   = (uint32_t*)(ws + 2355200);     // 1,310,720
    uint16_t* candIdx   = (uint16_t*)(ws + 3665920);     //   655,360
    uint32_t* meta      = (uint32_t*)(ws + 4321280);     //     2,560
    uint32_t* tkKey     = (uint32_t*)(ws + 4323840);     //    25,600
    uint32_t* tkIdx     = (uint32_t*)(ws + 4349440);     //    25,600

    decode_boxes<<<(NB * NPTS + 255) / 256, 256, 0, stream>>>(bb0, bb1, bb2, boxes);
    select_cands<<<NB * NCLS, TBA, 0, stream>>>(cls0, obj0, cls1, obj1, cls2, obj2,
                                                candKey, candIdx, meta);
    nms_walk<<<NB * NCLS, TBB, 0, stream>>>(cls0, obj0, cls1, obj1, cls2, obj2,
                                            boxes, candKey, candIdx, meta,
                                            keptScore, keptBox);
    topk_a<<<NB * 8, 256, 0, stream>>>(keptScore, tkKey, tkIdx);
    topk_b<<<NB, 256, 0, stream>>>(tkKey, tkIdx, keptBox, out);
}